// Round 9
// baseline (4175.125 us; speedup 1.0000x reference)
//
#include <hip/hip_runtime.h>
#include <stdint.h>

#define T_STEPS 200
#define OBSD    128
#define HID     128
#define LATD    32
#define BS_TOT  12800
#define KIN     160

#define OUT_ENT_OFF 81920000
#define OUT_LP_OFF  84480000

// lstm_main LDS layout (bytes)
#define WR_OFF  0          // 65536     : Wr bf16 frags, ks 0..1 only (lane-linear)
#define H_OFF   65536      // 2 x 16384 : h tile [64][128] bf16, XOR-swizzled, dbuf
#define WMU_OFF 98304      // 8192      : W_mu bf16 [32][128], XOR-swizzled
#define LDS_SZ  106496

#define L2E  1.4426950408889634f
#define L2E2 2.8853900817779268f
#define LOG2PI 1.8378770664093453f

typedef short  bf16x8 __attribute__((ext_vector_type(8)));
typedef float  f32x4  __attribute__((ext_vector_type(4)));
typedef uint32_t u32;
typedef u32    u32x4  __attribute__((ext_vector_type(4)));

// raw workgroup barrier: order LDS only, leave global loads/stores in flight
#define BAR() do {                                        \
    __builtin_amdgcn_sched_barrier(0);                    \
    asm volatile("s_waitcnt lgkmcnt(0)" ::: "memory");    \
    __builtin_amdgcn_s_barrier();                         \
    __builtin_amdgcn_sched_barrier(0);                    \
} while (0)

__device__ __forceinline__ uint16_t f2bf(float f) {
    u32 u = __builtin_bit_cast(u32, f);
    u32 r = (u + 0x7fffu + ((u >> 16) & 1u)) >> 16;
    return (uint16_t)r;
}
__device__ __forceinline__ float bf2f(u32 bits16) {
    u32 u = bits16 << 16;
    return __builtin_bit_cast(float, u);
}
__device__ __forceinline__ u32 pack2(float a, float b) {
    return (u32)f2bf(a) | ((u32)f2bf(b) << 16);
}
__device__ __forceinline__ u32 cvt_pk_bf16(float lo, float hi) {
    u32 r;
    asm("v_cvt_pk_bf16_f32 %0, %1, %2" : "=v"(r) : "v"(lo), "v"(hi));
    return r;
}
// x pre-scaled by L2E: sigmoid(x_true)
__device__ __forceinline__ float sig2(float x) {
    float e;
    asm("v_exp_f32 %0, -%1" : "=v"(e) : "v"(x));
    return __builtin_amdgcn_rcpf(1.f + e);
}
// x pre-scaled by 2*L2E: tanh(x_true)
__device__ __forceinline__ float tanh2(float x) {
    float e;
    asm("v_exp_f32 %0, %1" : "=v"(e) : "v"(x));
    return 1.f - 2.f * __builtin_amdgcn_rcpf(1.f + e);
}
// byte offset of h[row][col] in a [R][128] bf16 tile, XOR bank swizzle
__device__ __forceinline__ int hswz(int row, int col) {
    return ((row << 8) + (col << 1)) ^ ((row & 7) << 4);
}
// MFMA C-fragment from two bf16-pairs (xg): 1 VALU op per element
__device__ __forceinline__ f32x4 cfrag(u32 u01, u32 u23) {
    f32x4 c;
    c[0] = __builtin_bit_cast(float, u01 << 16);
    c[1] = __builtin_bit_cast(float, u01 & 0xffff0000u);
    c[2] = __builtin_bit_cast(float, u23 << 16);
    c[3] = __builtin_bit_cast(float, u23 & 0xffff0000u);
    return c;
}

// ---------------------------------------------------------------------------
// Kernel 1: xg = (x @ W_ihx^T + b_ih + b_hh + [t>0] zbias) * gate_scale, bf16,
// in the main kernel's fragment order. (unchanged, passing since round 5)
// ---------------------------------------------------------------------------
__global__ __launch_bounds__(512, 2) void xg_prep(
    const float* __restrict__ x,
    const float* __restrict__ W_ih,
    const float* __restrict__ b_ih,
    const float* __restrict__ b_hh,
    const float* __restrict__ b_mu,
    uint16_t* __restrict__ xg)
{
    const int blk = blockIdx.x;
    const int t   = blk >> 2, bq = blk & 3;
    const int tid = threadIdx.x;
    const int w = tid >> 6, l = tid & 63, lg = l >> 4, ln = l & 15;
    const int b0 = bq * 64;

    bf16x8 wb[4][4];
    float  bias[4];
    #pragma unroll
    for (int q = 0; q < 4; ++q) {
        const int col = q * 128 + w * 16 + ln;
        float zb = 0.f;
        #pragma unroll
        for (int j = 0; j < 32; ++j) zb += b_mu[j] * W_ih[col * KIN + 128 + j];
        bias[q] = b_ih[col] + b_hh[col] + (t > 0 ? zb : 0.f);
        #pragma unroll
        for (int ks = 0; ks < 4; ++ks) {
            bf16x8 v;
            #pragma unroll
            for (int e = 0; e < 8; ++e)
                v[e] = (short)f2bf(W_ih[col * KIN + ks * 32 + lg * 8 + e]);
            wb[ks][q] = v;
        }
    }

    f32x4 acc[4][4];
    const f32x4 vz = {0.f, 0.f, 0.f, 0.f};
    #pragma unroll
    for (int rt = 0; rt < 4; ++rt)
        #pragma unroll
        for (int q = 0; q < 4; ++q) acc[rt][q] = vz;

    #pragma unroll
    for (int ks = 0; ks < 4; ++ks) {
        bf16x8 a[4];
        #pragma unroll
        for (int rt = 0; rt < 4; ++rt) {
            const int brow = b0 + rt * 16 + ln;
            const float* src = x + ((size_t)brow * T_STEPS + t) * OBSD + ks * 32 + lg * 8;
            bf16x8 v;
            #pragma unroll
            for (int e = 0; e < 8; ++e) v[e] = (short)f2bf(src[e]);
            a[rt] = v;
        }
        #pragma unroll
        for (int rt = 0; rt < 4; ++rt)
            #pragma unroll
            for (int q = 0; q < 4; ++q)
                acc[rt][q] = __builtin_amdgcn_mfma_f32_16x16x32_bf16(
                    a[rt], wb[ks][q], acc[rt][q], 0, 0, 0);
    }

    const float gsc[4] = {L2E, L2E, L2E2, L2E};
    uint4* dst = (uint4*)xg + ((size_t)blk * 512 + tid) * 8;
    #pragma unroll
    for (int rt = 0; rt < 4; ++rt) {
        float v0[4], v1[4], v2[4], v3[4];
        #pragma unroll
        for (int e = 0; e < 4; ++e) {
            v0[e] = (acc[rt][0][e] + bias[0]) * gsc[0];
            v1[e] = (acc[rt][1][e] + bias[1]) * gsc[1];
            v2[e] = (acc[rt][2][e] + bias[2]) * gsc[2];
            v3[e] = (acc[rt][3][e] + bias[3]) * gsc[3];
        }
        uint4 o0, o1;
        o0.x = pack2(v0[0], v0[1]); o0.y = pack2(v0[2], v0[3]);
        o0.z = pack2(v1[0], v1[1]); o0.w = pack2(v1[2], v1[3]);
        o1.x = pack2(v2[0], v2[1]); o1.y = pack2(v2[2], v2[3]);
        o1.z = pack2(v3[0], v3[1]); o1.w = pack2(v3[2], v3[3]);
        dst[2 * rt]     = o0;
        dst[2 * rt + 1] = o1;
    }
}

// ---------------------------------------------------------------------------
// Kernel 2: recurrence (blocks 0..199) + lp/ent streaming fold (blocks
// 200..255, runs on otherwise-idle CUs). 1024 threads, 16 waves, 4/SIMD.
// Wave (wp = w&7, half = w>>3): gate cols q*128 + wp*16 + ln, rows
// (half*2+rt)*16. Wr ks{0,1} in LDS, ks{2,3} in regs. xg enters as MFMA C.
// eg A-frags reg-carried (no eps LDS). Single lgkm-barrier per step (h dbuf).
// ---------------------------------------------------------------------------
__global__ __launch_bounds__(1024, 4) void lstm_main(
    const float* __restrict__ eps,
    const float* __restrict__ W_ih,
    const float* __restrict__ W_hh,
    const float* __restrict__ W_mu,
    const float* __restrict__ b_mu,
    const float* __restrict__ cov,
    const uint16_t* __restrict__ xg,
    float* __restrict__ out)
{
    __shared__ __align__(16) char smem[LDS_SZ];

    const int tid = threadIdx.x;

    // ---- lp/ent fold on blocks 200..255 ----
    if (blockIdx.x >= 200) {
        float logdet = 0.f;
        for (int i = 0; i < LATD; ++i) logdet += logf(cov[i]);
        const float lconst = 32.f * LOG2PI + logdet;
        const float ec = 0.5f * 32.f * (1.f + LOG2PI) + 0.5f * logdet;
        const int base = (blockIdx.x - 200) * 1024 + tid;
        for (int j = base; j < T_STEPS * BS_TOT; j += 56 * 1024) {
            const float* ep = eps + (size_t)j * LATD;
            float ps = 0.f;
            #pragma unroll
            for (int k = 0; k < 8; ++k) {
                const float4 a = *(const float4*)(ep + k * 4);
                ps += a.x * a.x + a.y * a.y + a.z * a.z + a.w * a.w;
            }
            const int t = j / BS_TOT, row = j - t * BS_TOT;
            out[OUT_LP_OFF  + (size_t)row * 200 + t] = -0.5f * (ps + lconst);
            out[OUT_ENT_OFF + (size_t)row * 200 + t] = ec;
        }
        return;
    }

    const int w = tid >> 6, l = tid & 63, lg = l >> 4, ln = l & 15;
    const int wp = w & 7, half = w >> 3;

    // XCD-aware bijective swizzle over the 200 recurrence blocks
    const int xcd = blockIdx.x & 7;
    const int wk  = (xcd >> 1) + 4 * ((blockIdx.x >> 3) + 25 * (xcd & 1));
    const int bq  = wk & 3;
    const int bs0 = wk * 64;

    // stage W_mu f32 into H buf0 region for the Wr build
    {
        float* ws = (float*)(smem + H_OFF);
        for (int i = tid; i < 4096; i += 1024) ws[i] = W_mu[i];
    }
    __syncthreads();
    const float* wmu_s = (const float*)(smem + H_OFF);

    // W_mu bf16 region (swizzled), mean MFMA B-operand
    for (int i = tid; i < 2048; i += 1024) {
        const int col = i >> 6, k2 = (i & 63) * 2;
        const u32 p = pack2(wmu_s[col * HID + k2], wmu_s[col * HID + k2 + 1]);
        *(u32*)(smem + WMU_OFF + (((col << 8) + (k2 << 1)) ^ ((col & 7) << 4))) = p;
    }

    // weg = std * W_ihz * gate_scale (B-frags, K=32), in regs
    bf16x8 weg[4];
    {
        float stds[8];
        #pragma unroll
        for (int e = 0; e < 8; ++e) stds[e] = sqrtf(cov[lg * 8 + e]);
        const float gsc[4] = {L2E, L2E, L2E2, L2E};
        #pragma unroll
        for (int q = 0; q < 4; ++q) {
            const int col = q * 128 + wp * 16 + ln;
            bf16x8 v;
            #pragma unroll
            for (int e = 0; e < 8; ++e)
                v[e] = (short)f2bf(W_ih[col * KIN + 128 + lg * 8 + e] * stds[e] * gsc[q]);
            weg[q] = v;
        }
    }

    // Wr = (W_hh + W_ihz @ W_mu) * gate_scale: ks{0,1} -> LDS (half0 writes),
    // ks{2,3} -> registers (every wave keeps its own copy)
    bf16x8 wrr[2][4];
    #pragma unroll
    for (int q = 0; q < 4; ++q) {
        const float gs = (q == 2) ? L2E2 : L2E;
        const int col = q * 128 + wp * 16 + ln;
        float wzf[32];
        #pragma unroll
        for (int j4 = 0; j4 < 8; ++j4)
            *(float4*)&wzf[j4 * 4] = *(const float4*)&W_ih[col * KIN + 128 + j4 * 4];
        #pragma unroll
        for (int ks = 0; ks < 4; ++ks) {
            if (ks < 2 && half != 0) continue;   // LDS half built by half0 only
            float base[8];
            *(float4*)&base[0] = *(const float4*)&W_hh[col * HID + ks * 32 + lg * 8];
            *(float4*)&base[4] = *(const float4*)&W_hh[col * HID + ks * 32 + lg * 8 + 4];
            bf16x8 v;
            #pragma unroll
            for (int e = 0; e < 8; ++e) {
                float s = base[e];
                #pragma unroll
                for (int j = 0; j < 32; ++j)
                    s += wzf[j] * wmu_s[j * HID + ks * 32 + lg * 8 + e];
                v[e] = (short)f2bf(s * gs);
            }
            if (ks < 2)
                *(bf16x8*)(smem + WR_OFF + (((ks * 4 + q) * 8 + wp) << 10) + l * 16) = v;
            else
                wrr[ks - 2][q] = v;
        }
    }

    // mean-phase constants (half0 waves own z tile (rtm, ctm))
    const int rtm = (w >> 1) & 3, ctm = w & 1;
    const int zcol = ctm * 16 + ln;
    const float stdv = sqrtf(cov[zcol]);
    const float bmu  = b_mu[zcol];

    __syncthreads();   // WR/WMU written; wmu_s reads done

    // zero h buf0 (overwrites wmu_s region)
    for (int i = tid; i < 4096; i += 1024) ((u32*)(smem + H_OFF))[i] = 0;

    const f32x4 vz4 = {0.f, 0.f, 0.f, 0.f};
    f32x4 cst[2] = {vz4, vz4};
    u32x4 epf[2] = {{0, 0, 0, 0}, {0, 0, 0, 0}};

    __syncthreads();   // zeros visible

    for (int t = 0; t < T_STEPS; ++t) {
        const int pb = t & 1;
        const char* Hp = smem + H_OFF + pb * 16384;          // h_{t-1}
        char*       Hn = smem + H_OFF + (pb ^ 1) * 16384;    // h_t

        // ---- issue all global loads up front ----
        uint4 xv[4];
        const uint4* xp = (const uint4*)xg
            + ((size_t)(t * 4 + bq) * 512 + wp * 64 + l) * 8 + half * 4;
        #pragma unroll
        for (int i = 0; i < 4; ++i) xv[i] = xp[i];
        float4 fa[2], fb[2];   // eps[t] rows for next step's eg A-frags
        #pragma unroll
        for (int rt = 0; rt < 2; ++rt) {
            const float* ep = eps
                + ((size_t)t * BS_TOT + bs0 + (half * 2 + rt) * 16 + ln) * LATD + lg * 8;
            fa[rt] = *(const float4*)ep;
            fb[rt] = *(const float4*)(ep + 4);
        }
        float ez[4];           // eps[t-1] at (mean rows, zcol) for z_{t-1}
        if (half == 0) {
            const size_t eb = (size_t)(t > 0 ? t - 1 : 0) * BS_TOT + bs0 + rtm * 16 + lg * 4;
            #pragma unroll
            for (int e = 0; e < 4; ++e) ez[e] = eps[(eb + e) * LATD + zcol];
        }

        // ---- eg MFMA with C = xg (bias/x-part enters through C, no VALU add)
        f32x4 acc[2][4];
        #pragma unroll
        for (int rt = 0; rt < 2; ++rt) {
            const bf16x8 aE = __builtin_bit_cast(bf16x8, epf[rt]);
            const uint4 ua = xv[2 * rt], ub = xv[2 * rt + 1];
            acc[rt][0] = __builtin_amdgcn_mfma_f32_16x16x32_bf16(aE, weg[0], cfrag(ua.x, ua.y), 0, 0, 0);
            acc[rt][1] = __builtin_amdgcn_mfma_f32_16x16x32_bf16(aE, weg[1], cfrag(ua.z, ua.w), 0, 0, 0);
            acc[rt][2] = __builtin_amdgcn_mfma_f32_16x16x32_bf16(aE, weg[2], cfrag(ub.x, ub.y), 0, 0, 0);
            acc[rt][3] = __builtin_amdgcn_mfma_f32_16x16x32_bf16(aE, weg[3], cfrag(ub.z, ub.w), 0, 0, 0);
        }
        // ---- gates: h_{t-1} @ Wr^T (B: ks 0,1 from LDS, ks 2,3 from regs) ---
        #pragma unroll
        for (int ks = 0; ks < 4; ++ks) {
            bf16x8 a[2];
            #pragma unroll
            for (int rt = 0; rt < 2; ++rt)
                a[rt] = *(const bf16x8*)(Hp + hswz((half * 2 + rt) * 16 + ln, ks * 32 + lg * 8));
            #pragma unroll
            for (int q = 0; q < 4; ++q) {
                bf16x8 bfr;
                if (ks < 2)
                    bfr = *(const bf16x8*)(smem + WR_OFF + (((ks * 4 + q) * 8 + wp) << 10) + l * 16);
                else
                    bfr = wrr[ks - 2][q];
                #pragma unroll
                for (int rt = 0; rt < 2; ++rt)
                    acc[rt][q] = __builtin_amdgcn_mfma_f32_16x16x32_bf16(
                        a[rt], bfr, acc[rt][q], 0, 0, 0);
            }
        }
        // ---- mean/z for t-1 (half0 waves, off critical path) ----
        if (half == 0 && t > 0) {
            f32x4 macc = vz4;
            #pragma unroll
            for (int ks = 0; ks < 4; ++ks) {
                const bf16x8 am = *(const bf16x8*)(Hp + hswz(rtm * 16 + ln, ks * 32 + lg * 8));
                const bf16x8 bm = *(const bf16x8*)(smem + WMU_OFF + hswz(zcol, ks * 32 + lg * 8));
                macc = __builtin_amdgcn_mfma_f32_16x16x32_bf16(am, bm, macc, 0, 0, 0);
            }
            #pragma unroll
            for (int e = 0; e < 4; ++e)
                out[(size_t)(bs0 + rtm * 16 + lg * 4 + e) * 6400 + (t - 1) * 32 + zcol] =
                    macc[e] + bmu + ez[e] * stdv;
        }

        // ---- LSTM elementwise (acc already includes xg via C) ----
        #pragma unroll
        for (int rt = 0; rt < 2; ++rt) {
            float hv[4];
            #pragma unroll
            for (int e = 0; e < 4; ++e) {
                const float c = sig2(acc[rt][1][e]) * cst[rt][e]
                              + sig2(acc[rt][0][e]) * tanh2(acc[rt][2][e]);
                cst[rt][e] = c;
                hv[e] = sig2(acc[rt][3][e]) * tanh2(c * L2E2);
            }
            const u32 p01 = cvt_pk_bf16(hv[0], hv[1]);
            const u32 p23 = cvt_pk_bf16(hv[2], hv[3]);
            const int r0 = (half * 2 + rt) * 16 + lg * 4;
            const int hc = wp * 16 + ln;
            *(uint16_t*)(Hn + hswz(r0,     hc)) = (uint16_t)p01;
            *(uint16_t*)(Hn + hswz(r0 + 1, hc)) = (uint16_t)(p01 >> 16);
            *(uint16_t*)(Hn + hswz(r0 + 2, hc)) = (uint16_t)p23;
            *(uint16_t*)(Hn + hswz(r0 + 3, hc)) = (uint16_t)(p23 >> 16);
        }

        // ---- eps[t] -> bf16 A-frags for next step ----
        #pragma unroll
        for (int rt = 0; rt < 2; ++rt) {
            u32x4 pk;
            pk[0] = cvt_pk_bf16(fa[rt].x, fa[rt].y);
            pk[1] = cvt_pk_bf16(fa[rt].z, fa[rt].w);
            pk[2] = cvt_pk_bf16(fb[rt].x, fb[rt].y);
            pk[3] = cvt_pk_bf16(fb[rt].z, fb[rt].w);
            epf[rt] = pk;
        }

        BAR();   // single barrier: h_t visible; globals stay in flight
    }

    // epilogue: z for t = 199 (h_199 in buf0)
    if (half == 0) {
        const char* Hp = smem + H_OFF;
        f32x4 macc = vz4;
        #pragma unroll
        for (int ks = 0; ks < 4; ++ks) {
            const bf16x8 am = *(const bf16x8*)(Hp + hswz(rtm * 16 + ln, ks * 32 + lg * 8));
            const bf16x8 bm = *(const bf16x8*)(smem + WMU_OFF + hswz(zcol, ks * 32 + lg * 8));
            macc = __builtin_amdgcn_mfma_f32_16x16x32_bf16(am, bm, macc, 0, 0, 0);
        }
        const size_t eb = (size_t)199 * BS_TOT + bs0 + rtm * 16 + lg * 4;
        #pragma unroll
        for (int e = 0; e < 4; ++e) {
            const float evv = eps[(eb + e) * LATD + zcol];
            out[(size_t)(bs0 + rtm * 16 + lg * 4 + e) * 6400 + 199 * 32 + zcol] =
                macc[e] + bmu + evv * stdv;
        }
    }
}

extern "C" void kernel_launch(void* const* d_in, const int* in_sizes, int n_in,
                              void* d_out, int out_size, void* d_ws, size_t ws_size,
                              hipStream_t stream) {
    const float* x    = (const float*)d_in[0];
    const float* eps  = (const float*)d_in[1];
    const float* W_ih = (const float*)d_in[2];
    const float* W_hh = (const float*)d_in[3];
    const float* b_ih = (const float*)d_in[4];
    const float* b_hh = (const float*)d_in[5];
    const float* W_mu = (const float*)d_in[6];
    const float* b_mu = (const float*)d_in[7];
    const float* cov  = (const float*)d_in[8];
    float* out = (float*)d_out;
    uint16_t* xg = (uint16_t*)d_ws;   // 52,428,800 bytes

    hipLaunchKernelGGL(xg_prep, dim3(800), dim3(512), 0, stream, x, W_ih, b_ih, b_hh, b_mu, xg);
    hipLaunchKernelGGL(lstm_main, dim3(256), dim3(1024), 0, stream,
                       eps, W_ih, W_hh, W_mu, b_mu, cov, xg, out);
}

// Round 10
// 2037.902 us; speedup vs baseline: 2.0487x; 2.0487x over previous
//
#include <hip/hip_runtime.h>
#include <stdint.h>

#define T_STEPS 200
#define OBSD    128
#define HID     128
#define LATD    32
#define BS_TOT  12800
#define KIN     160

#define OUT_ENT_OFF 81920000
#define OUT_LP_OFF  84480000

// lstm_main LDS layout (bytes)
#define WR_OFF  0          // 131072 : Wr bf16 fragments (lane-linear)
#define H_OFF   131072     // 16384  : h tile [64][128] bf16, XOR-swizzled
#define WMU_OFF 147456     // 8192   : W_mu bf16 [32][128], XOR-swizzled
#define E_OFF   155648     // 4096   : eps_{t-1} bf16, A-fragment order
#define LDS_SZ  159744

#define L2E  1.4426950408889634f
#define L2E2 2.8853900817779268f
#define LOG2PI 1.8378770664093453f

typedef short  bf16x8 __attribute__((ext_vector_type(8)));
typedef float  f32x4  __attribute__((ext_vector_type(4)));
typedef uint32_t u32;

// raw workgroup barrier: order LDS only, leave global loads/stores in flight
#define BAR() do {                                        \
    __builtin_amdgcn_sched_barrier(0);                    \
    asm volatile("s_waitcnt lgkmcnt(0)" ::: "memory");    \
    __builtin_amdgcn_s_barrier();                         \
    __builtin_amdgcn_sched_barrier(0);                    \
} while (0)

__device__ __forceinline__ uint16_t f2bf(float f) {
    u32 u = __builtin_bit_cast(u32, f);
    u32 r = (u + 0x7fffu + ((u >> 16) & 1u)) >> 16;
    return (uint16_t)r;
}
__device__ __forceinline__ float bf2f(u32 bits16) {
    u32 u = bits16 << 16;
    return __builtin_bit_cast(float, u);
}
__device__ __forceinline__ u32 pack2(float a, float b) {
    return (u32)f2bf(a) | ((u32)f2bf(b) << 16);
}
__device__ __forceinline__ u32 cvt_pk_bf16(float lo, float hi) {
    u32 r;
    asm("v_cvt_pk_bf16_f32 %0, %1, %2" : "=v"(r) : "v"(lo), "v"(hi));
    return r;
}
// x pre-scaled by L2E: sigmoid(x_true)
__device__ __forceinline__ float sig2(float x) {
    float e;
    asm("v_exp_f32 %0, -%1" : "=v"(e) : "v"(x));
    return __builtin_amdgcn_rcpf(1.f + e);
}
// x pre-scaled by 2*L2E: tanh(x_true)
__device__ __forceinline__ float tanh2(float x) {
    float e;
    asm("v_exp_f32 %0, %1" : "=v"(e) : "v"(x));
    return 1.f - 2.f * __builtin_amdgcn_rcpf(1.f + e);
}
// byte offset of h[row][col] in a [R][128] bf16 tile, XOR bank swizzle
__device__ __forceinline__ int hswz(int row, int col) {
    return ((row << 8) + (col << 1)) ^ ((row & 7) << 4);
}
// MFMA C-fragment from two packed bf16-pairs (xg): 2 ops per pair
__device__ __forceinline__ f32x4 cfrag(u32 u01, u32 u23) {
    f32x4 c;
    c[0] = __builtin_bit_cast(float, u01 << 16);
    c[1] = __builtin_bit_cast(float, u01 & 0xffff0000u);
    c[2] = __builtin_bit_cast(float, u23 << 16);
    c[3] = __builtin_bit_cast(float, u23 & 0xffff0000u);
    return c;
}

// ---------------------------------------------------------------------------
// Kernel 1: xg = (x @ W_ihx^T + b_ih + b_hh + [t>0] zbias) * gate_scale, bf16,
// in the main kernel's fragment order. (unchanged, passing since round 5)
// ---------------------------------------------------------------------------
__global__ __launch_bounds__(512, 2) void xg_prep(
    const float* __restrict__ x,
    const float* __restrict__ W_ih,
    const float* __restrict__ b_ih,
    const float* __restrict__ b_hh,
    const float* __restrict__ b_mu,
    uint16_t* __restrict__ xg)
{
    const int blk = blockIdx.x;
    const int t   = blk >> 2, bq = blk & 3;
    const int tid = threadIdx.x;
    const int w = tid >> 6, l = tid & 63, lg = l >> 4, ln = l & 15;
    const int b0 = bq * 64;

    bf16x8 wb[4][4];
    float  bias[4];
    #pragma unroll
    for (int q = 0; q < 4; ++q) {
        const int col = q * 128 + w * 16 + ln;
        float zb = 0.f;
        #pragma unroll
        for (int j = 0; j < 32; ++j) zb += b_mu[j] * W_ih[col * KIN + 128 + j];
        bias[q] = b_ih[col] + b_hh[col] + (t > 0 ? zb : 0.f);
        #pragma unroll
        for (int ks = 0; ks < 4; ++ks) {
            bf16x8 v;
            #pragma unroll
            for (int e = 0; e < 8; ++e)
                v[e] = (short)f2bf(W_ih[col * KIN + ks * 32 + lg * 8 + e]);
            wb[ks][q] = v;
        }
    }

    f32x4 acc[4][4];
    const f32x4 vz = {0.f, 0.f, 0.f, 0.f};
    #pragma unroll
    for (int rt = 0; rt < 4; ++rt)
        #pragma unroll
        for (int q = 0; q < 4; ++q) acc[rt][q] = vz;

    #pragma unroll
    for (int ks = 0; ks < 4; ++ks) {
        bf16x8 a[4];
        #pragma unroll
        for (int rt = 0; rt < 4; ++rt) {
            const int brow = b0 + rt * 16 + ln;
            const float* src = x + ((size_t)brow * T_STEPS + t) * OBSD + ks * 32 + lg * 8;
            bf16x8 v;
            #pragma unroll
            for (int e = 0; e < 8; ++e) v[e] = (short)f2bf(src[e]);
            a[rt] = v;
        }
        #pragma unroll
        for (int rt = 0; rt < 4; ++rt)
            #pragma unroll
            for (int q = 0; q < 4; ++q)
                acc[rt][q] = __builtin_amdgcn_mfma_f32_16x16x32_bf16(
                    a[rt], wb[ks][q], acc[rt][q], 0, 0, 0);
    }

    const float gsc[4] = {L2E, L2E, L2E2, L2E};
    uint4* dst = (uint4*)xg + ((size_t)blk * 512 + tid) * 8;
    #pragma unroll
    for (int rt = 0; rt < 4; ++rt) {
        float v0[4], v1[4], v2[4], v3[4];
        #pragma unroll
        for (int e = 0; e < 4; ++e) {
            v0[e] = (acc[rt][0][e] + bias[0]) * gsc[0];
            v1[e] = (acc[rt][1][e] + bias[1]) * gsc[1];
            v2[e] = (acc[rt][2][e] + bias[2]) * gsc[2];
            v3[e] = (acc[rt][3][e] + bias[3]) * gsc[3];
        }
        uint4 o0, o1;
        o0.x = pack2(v0[0], v0[1]); o0.y = pack2(v0[2], v0[3]);
        o0.z = pack2(v1[0], v1[1]); o0.w = pack2(v1[2], v1[3]);
        o1.x = pack2(v2[0], v2[1]); o1.y = pack2(v2[2], v2[3]);
        o1.z = pack2(v3[0], v3[1]); o1.w = pack2(v3[2], v3[3]);
        dst[2 * rt]     = o0;
        dst[2 * rt + 1] = o1;
    }
}

// ---------------------------------------------------------------------------
// Kernel 2: recurrence (blocks 0..199) + lp/ent row-major streaming on the
// otherwise-idle CUs (blocks 200..212; 213..255 exit). R7 structure:
// Wr fully in LDS, E single-buffered, 2 lgkm-only barriers. New vs R7:
// xg enters the eg MFMA as the C operand (cfrag), prefetched one step ahead.
// ---------------------------------------------------------------------------
__global__ __launch_bounds__(1024, 4) void lstm_main(
    const float* __restrict__ eps,
    const float* __restrict__ W_ih,
    const float* __restrict__ W_hh,
    const float* __restrict__ W_mu,
    const float* __restrict__ b_mu,
    const float* __restrict__ cov,
    const uint16_t* __restrict__ xg,
    float* __restrict__ out)
{
    __shared__ __align__(16) char smem[LDS_SZ];

    const int tid = threadIdx.x;

    // ---- lp/ent fold: one row per thread, t-loop (coalesced both ways) ----
    if (blockIdx.x >= 200) {
        const int row = (blockIdx.x - 200) * 1024 + tid;
        if (row < BS_TOT) {
            float logdet = 0.f;
            for (int i = 0; i < LATD; ++i) logdet += logf(cov[i]);
            const float lconst = 32.f * LOG2PI + logdet;
            const float ec = 0.5f * 32.f * (1.f + LOG2PI) + 0.5f * logdet;
            const float* ep0 = eps + (size_t)row * LATD;
            float* lpw = out + OUT_LP_OFF  + (size_t)row * 200;
            float* enw = out + OUT_ENT_OFF + (size_t)row * 200;
            for (int t = 0; t < T_STEPS; ++t) {
                const float* ep = ep0 + (size_t)t * BS_TOT * LATD;
                float ps = 0.f;
                #pragma unroll
                for (int k = 0; k < 8; ++k) {
                    const float4 a = *(const float4*)(ep + k * 4);
                    ps += a.x * a.x + a.y * a.y + a.z * a.z + a.w * a.w;
                }
                lpw[t] = -0.5f * (ps + lconst);
                enw[t] = ec;
            }
        }
        return;
    }

    const int w = tid >> 6, l = tid & 63, lg = l >> 4, ln = l & 15;
    const int wp = w & 7, half = w >> 3;

    // XCD-aware bijective swizzle over the 200 recurrence blocks
    const int xcd = blockIdx.x & 7;
    const int wk  = (xcd >> 1) + 4 * ((blockIdx.x >> 3) + 25 * (xcd & 1));
    const int bq  = wk & 3;
    const int bs0 = wk * 64;

    // stage W_mu f32 into the (future) H region
    {
        float* ws = (float*)(smem + H_OFF);
        for (int i = tid; i < 4096; i += 1024) ws[i] = W_mu[i];
    }
    __syncthreads();
    const float* wmu_s = (const float*)(smem + H_OFF);

    // W_mu bf16 region (swizzled), for the mean MFMA B-operand
    for (int i = tid; i < 2048; i += 1024) {
        const int col = i >> 6, k2 = (i & 63) * 2;
        const u32 p = pack2(wmu_s[col * HID + k2], wmu_s[col * HID + k2 + 1]);
        *(u32*)(smem + WMU_OFF + (((col << 8) + (k2 << 1)) ^ ((col & 7) << 4))) = p;
    }

    // weg = std * W_ihz * gate_scale (B-frags, K=32), in regs
    bf16x8 weg[4];
    {
        float stds[8];
        #pragma unroll
        for (int e = 0; e < 8; ++e) stds[e] = sqrtf(cov[lg * 8 + e]);
        const float gsc[4] = {L2E, L2E, L2E2, L2E};
        #pragma unroll
        for (int q = 0; q < 4; ++q) {
            const int col = q * 128 + wp * 16 + ln;
            bf16x8 v;
            #pragma unroll
            for (int e = 0; e < 8; ++e)
                v[e] = (short)f2bf(W_ih[col * KIN + 128 + lg * 8 + e] * stds[e] * gsc[q]);
            weg[q] = v;
        }
    }

    // Wr = (W_hh + W_ihz @ W_mu) * gate_scale -> LDS. half0: q{0,1}, half1: q{2,3}
    #pragma unroll
    for (int qq = 0; qq < 2; ++qq) {
        const int q = half * 2 + qq;
        const float gs = (q == 2) ? L2E2 : L2E;
        const int col = q * 128 + wp * 16 + ln;
        float wzf[32];
        #pragma unroll
        for (int j4 = 0; j4 < 8; ++j4)
            *(float4*)&wzf[j4 * 4] = *(const float4*)&W_ih[col * KIN + 128 + j4 * 4];
        #pragma unroll
        for (int ks = 0; ks < 4; ++ks) {
            float base[8];
            *(float4*)&base[0] = *(const float4*)&W_hh[col * HID + ks * 32 + lg * 8];
            *(float4*)&base[4] = *(const float4*)&W_hh[col * HID + ks * 32 + lg * 8 + 4];
            bf16x8 v;
            #pragma unroll
            for (int e = 0; e < 8; ++e) {
                float s = base[e];
                #pragma unroll
                for (int j = 0; j < 32; ++j)
                    s += wzf[j] * wmu_s[j * HID + ks * 32 + lg * 8 + e];
                v[e] = (short)f2bf(s * gs);
            }
            *(bf16x8*)(smem + WR_OFF + (((ks * 4 + q) * 8 + wp) << 10) + l * 16) = v;
        }
    }

    // mean-phase constants (half0 waves own z tile (rtm, ctm))
    const int rtm = (w >> 1) & 3, ctm = w & 1;
    const int zcol = ctm * 16 + ln;
    const float stdv = sqrtf(cov[zcol]);
    const float bmu  = b_mu[zcol];

    __syncthreads();   // WR/WMU written; wmu_s reads done

    // zero h tile (overwrites wmu_s region) and E region
    for (int i = tid; i < 4096; i += 1024) ((u32*)(smem + H_OFF))[i] = 0;
    for (int i = tid; i < 1024; i += 1024) ((u32*)(smem + E_OFF))[i] = 0;

    const f32x4 vz4 = {0.f, 0.f, 0.f, 0.f};
    f32x4 cst[2] = {vz4, vz4};

    // eps load/store maps (thread -> (row, colpair) -> fragment-order byte)
    const int erow = tid >> 4, ecol = (tid & 15) * 2;
    const int ewr = ((erow >> 4) * 64 + (ecol >> 3) * 16 + (erow & 15)) * 16 + (ecol & 7) * 2;

    // loop-invariant LDS byte offsets
    const int wrb = (wp << 10) + l * 16;                 // Wr: + (ks*4+q)*8192
    const int egb = E_OFF + ((half * 2) * 64 + l) * 16;  // E A-frag: + rt*1024

    // prologue: prefetch xg[t=0] fragments
    uint4 xvp[4];
    {
        const uint4* xp = (const uint4*)xg
            + ((size_t)(0 * 4 + bq) * 512 + wp * 64 + l) * 8 + half * 4;
        #pragma unroll
        for (int i = 0; i < 4; ++i) xvp[i] = xp[i];
    }

    __syncthreads();   // h zeros + E zeros visible

    for (int t = 0; t < T_STEPS; ++t) {
        // ---- acc <- xg C-fragments (xvp holds xg[t]; dies here) ----
        f32x4 acc[2][4];
        #pragma unroll
        for (int rt = 0; rt < 2; ++rt) {
            const uint4 ua = xvp[2 * rt], ub = xvp[2 * rt + 1];
            acc[rt][0] = cfrag(ua.x, ua.y);
            acc[rt][1] = cfrag(ua.z, ua.w);
            acc[rt][2] = cfrag(ub.x, ub.y);
            acc[rt][3] = cfrag(ub.z, ub.w);
        }

        // ---- issue next-step xg + this-step eps loads ----
        const int tn = (t + 1 < T_STEPS) ? t + 1 : t;
        {
            const uint4* xp = (const uint4*)xg
                + ((size_t)(tn * 4 + bq) * 512 + wp * 64 + l) * 8 + half * 4;
            #pragma unroll
            for (int i = 0; i < 4; ++i) xvp[i] = xp[i];
        }
        const float2 fev = *(const float2*)(eps + ((size_t)t * BS_TOT + bs0 + erow) * LATD + ecol);

        // ---- eg: eps_{t-1} @ weg^T, C = xg (E reads; ks0 operands land) ----
        const bf16x8 aE0 = *(const bf16x8*)(smem + egb);
        const bf16x8 aE1 = *(const bf16x8*)(smem + egb + 1024);
        bf16x8 a0[2], b0[4], a1[2], b1[4];
        #pragma unroll
        for (int rt = 0; rt < 2; ++rt)
            a0[rt] = *(const bf16x8*)(smem + H_OFF + hswz((half * 2 + rt) * 16 + ln, lg * 8));
        #pragma unroll
        for (int q = 0; q < 4; ++q)
            b0[q] = *(const bf16x8*)(smem + WR_OFF + wrb + q * 8192);
        #pragma unroll
        for (int q = 0; q < 4; ++q) {
            acc[0][q] = __builtin_amdgcn_mfma_f32_16x16x32_bf16(aE0, weg[q], acc[0][q], 0, 0, 0);
            acc[1][q] = __builtin_amdgcn_mfma_f32_16x16x32_bf16(aE1, weg[q], acc[1][q], 0, 0, 0);
        }
        // ---- gates: h_{t-1} @ Wr^T, pipelined over ks ----
        #pragma unroll
        for (int ks = 0; ks < 4; ++ks) {
            if (ks < 3) {
                #pragma unroll
                for (int rt = 0; rt < 2; ++rt)
                    a1[rt] = *(const bf16x8*)(smem + H_OFF
                        + hswz((half * 2 + rt) * 16 + ln, (ks + 1) * 32 + lg * 8));
                #pragma unroll
                for (int q = 0; q < 4; ++q)
                    b1[q] = *(const bf16x8*)(smem + WR_OFF + wrb + ((ks + 1) * 4 + q) * 8192);
            }
            #pragma unroll
            for (int rt = 0; rt < 2; ++rt)
                #pragma unroll
                for (int q = 0; q < 4; ++q)
                    acc[rt][q] = __builtin_amdgcn_mfma_f32_16x16x32_bf16(
                        a0[rt], b0[q], acc[rt][q], 0, 0, 0);
            #pragma unroll
            for (int rt = 0; rt < 2; ++rt) a0[rt] = a1[rt];
            #pragma unroll
            for (int q = 0; q < 4; ++q) b0[q] = b1[q];
        }
        // ---- mean/z for t-1 (half0 waves, off critical path) ----
        if (half == 0 && t > 0) {
            f32x4 macc = vz4;
            #pragma unroll
            for (int ks = 0; ks < 4; ++ks) {
                const bf16x8 am = *(const bf16x8*)(smem + H_OFF + hswz(rtm * 16 + ln, ks * 32 + lg * 8));
                const bf16x8 bm = *(const bf16x8*)(smem + WMU_OFF + hswz(zcol, ks * 32 + lg * 8));
                macc = __builtin_amdgcn_mfma_f32_16x16x32_bf16(am, bm, macc, 0, 0, 0);
            }
            #pragma unroll
            for (int e = 0; e < 4; ++e) {
                const int row = rtm * 16 + lg * 4 + e;
                const float evv = bf2f(*(const uint16_t*)(
                    smem + E_OFF + ((rtm * 64 + (zcol >> 3) * 16 + (lg * 4 + e)) << 4) + (zcol & 7) * 2));
                out[(size_t)(bs0 + row) * 6400 + (t - 1) * 32 + zcol] =
                    macc[e] + bmu + evv * stdv;
            }
        }

        BAR();   // barA: all H/E reads of P0 done; globals stay in flight

        // ---- P1: store eps_t into E (for step t+1) ----
        *(u32*)(smem + E_OFF + ewr) = cvt_pk_bf16(fev.x, fev.y);

        // LSTM elementwise: gates already complete in acc (xg entered via C)
        #pragma unroll
        for (int rt = 0; rt < 2; ++rt) {
            float hv[4];
            #pragma unroll
            for (int e = 0; e < 4; ++e) {
                const float c = sig2(acc[rt][1][e]) * cst[rt][e]
                              + sig2(acc[rt][0][e]) * tanh2(acc[rt][2][e]);
                cst[rt][e] = c;
                hv[e] = sig2(acc[rt][3][e]) * tanh2(c * L2E2);
            }
            const u32 p01 = cvt_pk_bf16(hv[0], hv[1]);
            const u32 p23 = cvt_pk_bf16(hv[2], hv[3]);
            const int r0 = (half * 2 + rt) * 16 + lg * 4;
            const int hc = wp * 16 + ln;
            *(uint16_t*)(smem + H_OFF + hswz(r0,     hc)) = (uint16_t)p01;
            *(uint16_t*)(smem + H_OFF + hswz(r0 + 1, hc)) = (uint16_t)(p01 >> 16);
            *(uint16_t*)(smem + H_OFF + hswz(r0 + 2, hc)) = (uint16_t)p23;
            *(uint16_t*)(smem + H_OFF + hswz(r0 + 3, hc)) = (uint16_t)(p23 >> 16);
        }

        BAR();   // barB: h_t + eps_t visible
    }

    // epilogue: z for t = 199 (E holds eps_199, H holds h_199)
    if (half == 0) {
        f32x4 macc = vz4;
        #pragma unroll
        for (int ks = 0; ks < 4; ++ks) {
            const bf16x8 am = *(const bf16x8*)(smem + H_OFF + hswz(rtm * 16 + ln, ks * 32 + lg * 8));
            const bf16x8 bm = *(const bf16x8*)(smem + WMU_OFF + hswz(zcol, ks * 32 + lg * 8));
            macc = __builtin_amdgcn_mfma_f32_16x16x32_bf16(am, bm, macc, 0, 0, 0);
        }
        #pragma unroll
        for (int e = 0; e < 4; ++e) {
            const int row = rtm * 16 + lg * 4 + e;
            const float evv = bf2f(*(const uint16_t*)(
                smem + E_OFF + ((rtm * 64 + (zcol >> 3) * 16 + (lg * 4 + e)) << 4) + (zcol & 7) * 2));
            out[(size_t)(bs0 + row) * 6400 + 199 * 32 + zcol] =
                macc[e] + bmu + evv * stdv;
        }
    }
}

extern "C" void kernel_launch(void* const* d_in, const int* in_sizes, int n_in,
                              void* d_out, int out_size, void* d_ws, size_t ws_size,
                              hipStream_t stream) {
    const float* x    = (const float*)d_in[0];
    const float* eps  = (const float*)d_in[1];
    const float* W_ih = (const float*)d_in[2];
    const float* W_hh = (const float*)d_in[3];
    const float* b_ih = (const float*)d_in[4];
    const float* b_hh = (const float*)d_in[5];
    const float* W_mu = (const float*)d_in[6];
    const float* b_mu = (const float*)d_in[7];
    const float* cov  = (const float*)d_in[8];
    float* out = (float*)d_out;
    uint16_t* xg = (uint16_t*)d_ws;   // 52,428,800 bytes

    hipLaunchKernelGGL(xg_prep, dim3(800), dim3(512), 0, stream, x, W_ih, b_ih, b_hh, b_mu, xg);
    hipLaunchKernelGGL(lstm_main, dim3(256), dim3(1024), 0, stream,
                       eps, W_ih, W_hh, W_mu, b_mu, cov, xg, out);
}